// Round 10
// baseline (92.993 us; speedup 1.0000x reference)
//
#include <hip/hip_runtime.h>
#include <stdint.h>

// Problem constants (B,C,H,W)=(4,128,64,128), R=4, D=9, out channels 81.
// out[b, di*9+dj, h, w] = sum_c src[b,c,h,w] * tgt[b,c,h+di-8,w+dj-8]
// (zero when the shifted index leaves [0,H)x[0,W); shifts are [-8,0]).
//
// v11: single kernel, h-span blocking + LDS sliding window.
// Unified R0-R9 model: every version is far-read-volume bound at ~6 TB/s
// (LLC rate; inter-kernel L2 invalidation defeats placement tricks, so
// v10's XCD alignment was null). Volume is the only lever:
//   v9/v10: 50 MB converter + 138 MB main.  v11: 92 MB, one dispatch.
// Block = (b, h-span of 4, w-quarter) -> 256 blocks, 576 thr (9 waves).
// Stages f32->bf16 once per slice: 4 src slices (32 cols) + 12 tgt slices
// (48 cols = 16-col halo + 32) into a 9-slot LDS ring (157 KB), sliding
// +1 tgt slice per h. wave = di; per h: 4 band tiles x K=128 = 16 MFMA
// (fragments = one ds_read_b128 each, m92 pattern, padded oct-rows).
// Band extraction, swizzle, wedge-masked store: v9's verified formulas.
#define NB 4
#define NC 128
#define NH 64
#define NW 128
#define HW (NH * NW)      // 8192
#define ND 9
#define NOUT (ND * ND)    // 81
#define SH 4              // h rows per block
#define QW 32             // w-quarter width
#define TROW 392          // halfwords per oct-row, tgt slice (48*8 + 8 pad)
#define SROW 264          // halfwords per oct-row, src slice (32*8 + 8 pad)
#define OTILE (ND * 32)   // floats per di slice of outlds

typedef __attribute__((ext_vector_type(8))) short short8;
typedef __attribute__((ext_vector_type(4))) float f32x4;

__device__ __forceinline__ ushort f2bf(float f) {  // RNE f32->bf16
  uint u = __float_as_uint(f);
  u += 0x7FFFu + ((u >> 16) & 1u);
  return (ushort)(u >> 16);
}

__global__ __launch_bounds__(576, 1) void costvol_kernel(const float* __restrict__ src,
                                                         const float* __restrict__ tgt,
                                                         float* __restrict__ out) {
  __shared__ ushort tgtS[9][16 * TROW];   // 112.9 KB ring of tgt slices
  __shared__ ushort srcS[SH][16 * SROW];  // 33.8 KB src slices
  __shared__ float  outlds[ND * OTILE];   // 10.4 KB band tile (per h)

  const int tid  = threadIdx.x;
  const int lane = tid & 63;
  const int wave = tid >> 6;              // 0..8 == di
  const int col  = lane & 15;
  const int g    = lane >> 4;

  // decode: 256 blocks = 8 xcd * 32. combo=(b*4+q) pinned to xcd (mod 8),
  // h0 ascending within an xcd for temporal tgt-column reuse.
  const int xcd   = blockIdx.x & 7;
  const int r     = blockIdx.x >> 3;      // 0..31
  const int combo = ((r >> 4) << 3) | xcd;
  const int b     = combo >> 2;
  const int q     = combo & 3;
  const int h0    = (r & 15) << 2;

  const float* sb = src + (size_t)(b * NC) * HW;
  const float* tb = tgt + (size_t)(b * NC) * HW;

  // stage tgt slice row y -> ring slot y%9: 12 f4-cols x 128 c cells.
  // K-panel layout [oct=c>>3][lcol][c&7]; left halo cols <0 are clamped
  // (finite garbage, consumed only under the wedge mask).
  auto stage_tgt = [&](int y) {
    ushort* dstS = tgtS[y % 9];
    const float* py = tb + (size_t)y * NW;
    for (int cell = tid; cell < 12 * 128; cell += 576) {
      const int fc = cell % 12;
      const int c  = cell / 12;
      const int g0 = q * QW - 16 + 4 * fc;        // quad all-in or all-out
      const float4 v = *(const float4*)(py + (size_t)c * HW + (g0 < 0 ? 0 : g0));
      ushort* d = dstS + (c >> 3) * TROW + (4 * fc) * 8 + (c & 7);
      d[0]  = f2bf(v.x);
      d[8]  = f2bf(v.y);
      d[16] = f2bf(v.z);
      d[24] = f2bf(v.w);
    }
  };
  auto stage_src = [&](int hh) {
    ushort* dstS = srcS[hh];
    const float* ph = sb + (size_t)(h0 + hh) * NW + q * QW;
    for (int cell = tid; cell < 8 * 128; cell += 576) {
      const int fc = cell % 8;
      const int c  = cell / 8;
      const float4 v = *(const float4*)(ph + (size_t)c * HW + 4 * fc);
      ushort* d = dstS + (c >> 3) * SROW + (4 * fc) * 8 + (c & 7);
      d[0]  = f2bf(v.x);
      d[8]  = f2bf(v.y);
      d[16] = f2bf(v.z);
      d[24] = f2bf(v.w);
    }
  };

  // prologue: all src slices + initial 9-slot tgt window
#pragma unroll
  for (int hh = 0; hh < SH; ++hh) stage_src(hh);
  for (int y = h0 - 8; y <= h0; ++y)
    if (y >= 0) stage_tgt(y);
  __syncthreads();

  for (int hh = 0; hh < SH; ++hh) {
    const int h = h0 + hh;
    const int y = h + wave - 8;           // this wave's tgt row (di = wave)
    if (y >= 0) {
      const ushort* Bp = tgtS[y % 9];
      const ushort* Ap = srcS[hh];
      // m-tiles at local w {0,16}; n-tiles at local col {0,16,32}
      // (local n 0 == global w' = 32q-16). diag(m)=B(m+16), sub(m)=B(m).
      f32x4 aD0 = {0.f,0.f,0.f,0.f}, aS0 = {0.f,0.f,0.f,0.f};
      f32x4 aD1 = {0.f,0.f,0.f,0.f}, aS1 = {0.f,0.f,0.f,0.f};
#pragma unroll
      for (int kk = 0; kk < 4; ++kk) {
        const int ro = 4 * kk + g;
        const short8 A0 = *(const short8*)&Ap[ro * SROW + col * 8];
        const short8 A1 = *(const short8*)&Ap[ro * SROW + (16 + col) * 8];
        const short8 B0 = *(const short8*)&Bp[ro * TROW + col * 8];
        const short8 B1 = *(const short8*)&Bp[ro * TROW + (16 + col) * 8];
        const short8 B2 = *(const short8*)&Bp[ro * TROW + (32 + col) * 8];
        aS0 = __builtin_amdgcn_mfma_f32_16x16x32_bf16(A0, B0, aS0, 0, 0, 0);
        aD0 = __builtin_amdgcn_mfma_f32_16x16x32_bf16(A0, B1, aD0, 0, 0, 0);
        aS1 = __builtin_amdgcn_mfma_f32_16x16x32_bf16(A1, B1, aS1, 0, 0, 0);
        aD1 = __builtin_amdgcn_mfma_f32_16x16x32_bf16(A1, B2, aD1, 0, 0, 0);
      }
      // band extraction (v9-verified): C/D layout col=lane&15, row=4g+qr.
      // diag: dj=ncol-row+8 (row+dj>=8); sub: dj=ncol-row-8 (row+dj<=7) —
      // exact partition, every (row,dj,w) slot written once. Swizzle
      // (wl+4*dj)&31 spreads the dj-stride across banks.
      float* ol = &outlds[wave * OTILE];
#pragma unroll
      for (int qr = 0; qr < 4; ++qr) {
        const int row = 4 * g + qr;
        const int djd = col - row + 8;
        const int djs = col - row - 8;
        if (djd >= 0 && djd <= 8) {
          ol[djd * 32 + ((row + 4 * djd) & 31)]      = aD0[qr];
          ol[djd * 32 + ((16 + row + 4 * djd) & 31)] = aD1[qr];
        }
        if (djs >= 0 && djs <= 8) {
          ol[djs * 32 + ((row + 4 * djs) & 31)]      = aS0[qr];
          ol[djs * 32 + ((16 + row + 4 * djs) & 31)] = aS1[qr];
        }
      }
    }
    __syncthreads();                      // scatter done

    // store this h (9 di x 9 dj x 32 w, float4) + slide ring by one.
    // Zeros for y<0 planes and the w+dj<8 wedge (stale LDS never leaks).
    for (int s = tid; s < ND * ND * 8; s += 576) {
      const int di = s / 72;
      const int rr = s % 72;
      const int dj = rr >> 3;
      const int w4 = (rr & 7) << 2;
      f32x4 o = *(const f32x4*)&outlds[di * OTILE + dj * 32 + ((w4 + 4 * dj) & 31)];
      const bool vb = (h + di - 8) >= 0;
      const int wg = q * QW + w4;
#pragma unroll
      for (int i = 0; i < 4; ++i)
        if (!vb || (wg + i + dj < 8)) o[i] = 0.f;
      *(f32x4*)(out + ((size_t)((b * NOUT + di * ND + dj) * NH + h)) * NW + wg) = o;
    }
    if (hh < SH - 1) stage_tgt(h + 1);    // overwrites slot of y=h-8 (dead)
    __syncthreads();                      // outlds read + new slice ready
  }
}

extern "C" void kernel_launch(void* const* d_in, const int* in_sizes, int n_in,
                              void* d_out, int out_size, void* d_ws, size_t ws_size,
                              hipStream_t stream) {
  const float* src = (const float*)d_in[0];
  const float* tgt = (const float*)d_in[1];
  float* out = (float*)d_out;
  costvol_kernel<<<dim3(256), dim3(576), 0, stream>>>(src, tgt, out);
}

// Round 11
// 86.077 us; speedup vs baseline: 1.0803x; 1.0803x over previous
//
#include <hip/hip_runtime.h>
#include <stdint.h>

// Problem constants (B,C,H,W)=(4,128,64,128), R=4, D=9, out channels 81.
// out[b, di*9+dj, h, w] = sum_c src[b,c,h,w] * tgt[b,c,h+di-8,w+dj-8]
// (zero when the shifted index leaves [0,H)x[0,W); shifts are [-8,0]).
//
// v12 = v11 with the staging LDS-write storm removed.
// R10 accounting: v11's K-panel staging wrote 4 scattered ds_write_b16 per
// float4 -> 90K b16 LDS ops/block; 90K ops / 37us = 1.01 op/cyc: the
// kernel was LDS-ISSUE-bound, not volume-bound. v12 staging: each thread
// owns (col-quad x 8 consecutive channels): 8 coalesced global_load_dwordx4,
// pack in-register, 4 ds_write_b128 (8 contiguous bf16 = one oct-row
// segment). LDS ops 90K -> 11.3K/block. Steady-state slide uses T14
// issue-early (loads before MFMA phase, cvt+write after the barrier).
// Block/grid/MFMA/band-extraction/store: identical to v11 (absmax 0.25).
#define NB 4
#define NC 128
#define NH 64
#define NW 128
#define HW (NH * NW)      // 8192
#define ND 9
#define NOUT (ND * ND)    // 81
#define SH 4              // h rows per block
#define QW 32             // w-quarter width
#define TROW 392          // halfwords per oct-row, tgt slice (48*8 + 8 pad)
#define SROW 264          // halfwords per oct-row, src slice (32*8 + 8 pad)
#define OTILE (ND * 32)   // floats per di slice of outlds

typedef __attribute__((ext_vector_type(8))) short short8;
typedef __attribute__((ext_vector_type(4))) float f32x4;

__device__ __forceinline__ ushort f2bf(float f) {  // RNE f32->bf16
  uint u = __float_as_uint(f);
  u += 0x7FFFu + ((u >> 16) & 1u);
  return (ushort)(u >> 16);
}

__global__ __launch_bounds__(576, 1) void costvol_kernel(const float* __restrict__ src,
                                                         const float* __restrict__ tgt,
                                                         float* __restrict__ out) {
  __shared__ ushort tgtS[9][16 * TROW];   // 112.9 KB ring of tgt slices
  __shared__ ushort srcS[SH][16 * SROW];  // 33.8 KB src slices
  __shared__ float  outlds[ND * OTILE];   // 10.4 KB band tile (per h)

  const int tid  = threadIdx.x;
  const int lane = tid & 63;
  const int wave = tid >> 6;              // 0..8 == di
  const int col  = lane & 15;
  const int g    = lane >> 4;

  // decode: 256 blocks = 8 xcd * 32. combo=(b*4+q) pinned to xcd (mod 8),
  // h0 ascending within an xcd so h-span sharers of a tgt row co-reside.
  const int xcd   = blockIdx.x & 7;
  const int r     = blockIdx.x >> 3;      // 0..31
  const int combo = ((r >> 4) << 3) | xcd;
  const int b     = combo >> 2;
  const int q     = combo & 3;
  const int h0    = (r & 15) << 2;

  const float* sb = src + (size_t)(b * NC) * HW;
  const float* tb = tgt + (size_t)(b * NC) * HW;

  // ---- prologue: src slices (4 x 128 cells) ----
  // cell = (hh, oct o, col-quad fc): 8 float4 loads (c = 8o..8o+7), pack,
  // 4 ds_write_b128 at [o][4fc+i][0..7].
  for (int cell = tid; cell < SH * 128; cell += 576) {
    const int hh = cell >> 7;
    const int cc = cell & 127;
    const int fc = cc & 7;
    const int o  = cc >> 3;
    const float* p = sb + (size_t)(h0 + hh) * NW + q * QW + 4 * fc + (size_t)(o * 8) * HW;
    float4 v[8];
#pragma unroll
    for (int j = 0; j < 8; ++j) v[j] = *(const float4*)(p + (size_t)j * HW);
    ushort* d = srcS[hh] + o * SROW + (4 * fc) * 8;
#pragma unroll
    for (int i = 0; i < 4; ++i) {
      short8 e;
#pragma unroll
      for (int j = 0; j < 8; ++j) e[j] = (short)f2bf(((const float*)&v[j])[i]);
      *(short8*)&d[i * 8] = e;
    }
  }
  // ---- prologue: initial tgt window, rows y0..h0 (<=9 slices x 192 cells)
  // Left halo cols <0 clamped (finite garbage, consumed only under the
  // wedge mask in the store pass).
  {
    const int y0  = (h0 >= 8) ? h0 - 8 : 0;
    const int nts = h0 - y0 + 1;
    for (int cell = tid; cell < nts * 192; cell += 576) {
      const int y  = y0 + cell / 192;
      const int cc = cell % 192;
      const int fc = cc % 12;
      const int o  = cc / 12;
      const int g0 = q * QW - 16 + 4 * fc;       // quad all-in or all-out
      const float* p = tb + (size_t)y * NW + (g0 < 0 ? 0 : g0) + (size_t)(o * 8) * HW;
      float4 v[8];
#pragma unroll
      for (int j = 0; j < 8; ++j) v[j] = *(const float4*)(p + (size_t)j * HW);
      ushort* d = tgtS[y % 9] + o * TROW + (4 * fc) * 8;
#pragma unroll
      for (int i = 0; i < 4; ++i) {
        short8 e;
#pragma unroll
        for (int j = 0; j < 8; ++j) e[j] = (short)f2bf(((const float*)&v[j])[i]);
        *(short8*)&d[i * 8] = e;
      }
    }
  }
  __syncthreads();

  for (int hh = 0; hh < SH; ++hh) {
    const int h = h0 + hh;

    // T14 issue-early: next tgt slice's loads (192 staging threads, 8
    // float4 each) issued BEFORE the MFMA phase; cvt+ds_write after the
    // barrier (slot (h+1)%9 holds y=h-8, still read by wave 0 this h).
    float4 pv[8];
    const bool hs = (hh < SH - 1) && (tid < 192);
    int sfc = 0, so = 0;
    if (hs) {
      sfc = tid % 12;
      so  = tid / 12;
      const int g0 = q * QW - 16 + 4 * sfc;
      const float* p = tb + (size_t)(h + 1) * NW + (g0 < 0 ? 0 : g0) + (size_t)(so * 8) * HW;
#pragma unroll
      for (int j = 0; j < 8; ++j) pv[j] = *(const float4*)(p + (size_t)j * HW);
    }

    const int y = h + wave - 8;           // this wave's tgt row (di = wave)
    if (y >= 0) {
      const ushort* Bp = tgtS[y % 9];
      const ushort* Ap = srcS[hh];
      // m-tiles at local w {0,16}; n-tiles at local col {0,16,32}
      // (local n 0 == global w' = 32q-16). diag(m)=B(m+16), sub(m)=B(m).
      f32x4 aD0 = {0.f,0.f,0.f,0.f}, aS0 = {0.f,0.f,0.f,0.f};
      f32x4 aD1 = {0.f,0.f,0.f,0.f}, aS1 = {0.f,0.f,0.f,0.f};
#pragma unroll
      for (int kk = 0; kk < 4; ++kk) {
        const int ro = 4 * kk + g;
        const short8 A0 = *(const short8*)&Ap[ro * SROW + col * 8];
        const short8 A1 = *(const short8*)&Ap[ro * SROW + (16 + col) * 8];
        const short8 B0 = *(const short8*)&Bp[ro * TROW + col * 8];
        const short8 B1 = *(const short8*)&Bp[ro * TROW + (16 + col) * 8];
        const short8 B2 = *(const short8*)&Bp[ro * TROW + (32 + col) * 8];
        aS0 = __builtin_amdgcn_mfma_f32_16x16x32_bf16(A0, B0, aS0, 0, 0, 0);
        aD0 = __builtin_amdgcn_mfma_f32_16x16x32_bf16(A0, B1, aD0, 0, 0, 0);
        aS1 = __builtin_amdgcn_mfma_f32_16x16x32_bf16(A1, B1, aS1, 0, 0, 0);
        aD1 = __builtin_amdgcn_mfma_f32_16x16x32_bf16(A1, B2, aD1, 0, 0, 0);
      }
      // band extraction (v9/v11-verified): C/D layout col=lane&15, row=4g+qr.
      // diag: dj=ncol-row+8 (row+dj>=8); sub: dj=ncol-row-8 (row+dj<=7) —
      // exact partition, every (row,dj,w) slot written once. Swizzle
      // (wl+4*dj)&31 spreads the dj-stride across banks.
      float* ol = &outlds[wave * OTILE];
#pragma unroll
      for (int qr = 0; qr < 4; ++qr) {
        const int row = 4 * g + qr;
        const int djd = col - row + 8;
        const int djs = col - row - 8;
        if (djd >= 0 && djd <= 8) {
          ol[djd * 32 + ((row + 4 * djd) & 31)]      = aD0[qr];
          ol[djd * 32 + ((16 + row + 4 * djd) & 31)] = aD1[qr];
        }
        if (djs >= 0 && djs <= 8) {
          ol[djs * 32 + ((row + 4 * djs) & 31)]      = aS0[qr];
          ol[djs * 32 + ((16 + row + 4 * djs) & 31)] = aS1[qr];
        }
      }
    }
    __syncthreads();                      // scatter done

    // store this h (9 di x 9 dj x 32 w, float4). Zeros for y<0 planes and
    // the w+dj<8 wedge (stale/garbage LDS never leaks through the masks).
    for (int s = tid; s < ND * ND * 8; s += 576) {
      const int di = s / 72;
      const int rr = s % 72;
      const int dj = rr >> 3;
      const int w4 = (rr & 7) << 2;
      f32x4 o = *(const f32x4*)&outlds[di * OTILE + dj * 32 + ((w4 + 4 * dj) & 31)];
      const bool vb = (h + di - 8) >= 0;
      const int wg = q * QW + w4;
#pragma unroll
      for (int i = 0; i < 4; ++i)
        if (!vb || (wg + i + dj < 8)) o[i] = 0.f;
      *(f32x4*)(out + ((size_t)((b * NOUT + di * ND + dj) * NH + h)) * NW + wg) = o;
    }

    // T14 write-late: land the pre-loaded slice into the freed ring slot.
    if (hs) {
      ushort* d = tgtS[(h + 1) % 9] + so * TROW + (4 * sfc) * 8;
#pragma unroll
      for (int i = 0; i < 4; ++i) {
        short8 e;
#pragma unroll
        for (int j = 0; j < 8; ++j) e[j] = (short)f2bf(((const float*)&pv[j])[i]);
        *(short8*)&d[i * 8] = e;
      }
    }
    __syncthreads();                      // outlds read + new slice ready
  }
}

extern "C" void kernel_launch(void* const* d_in, const int* in_sizes, int n_in,
                              void* d_out, int out_size, void* d_ws, size_t ws_size,
                              hipStream_t stream) {
  const float* src = (const float*)d_in[0];
  const float* tgt = (const float*)d_in[1];
  float* out = (float*)d_out;
  costvol_kernel<<<dim3(256), dim3(576), 0, stream>>>(src, tgt, out);
}